// Round 1
// baseline (278.661 us; speedup 1.0000x reference)
//
#include <hip/hip_runtime.h>
#include <stdint.h>

#define N_NODES 100000
#define N_EDGES 600000
#define FEAT 128

typedef __attribute__((ext_vector_type(8))) short short8;
typedef __attribute__((ext_vector_type(4))) float floatx4;

__device__ __forceinline__ short f2bf(float f) {
    unsigned u = __builtin_bit_cast(unsigned, f);
    u = (u + 0x7FFFu + ((u >> 16) & 1u)) >> 16;   // RNE to bf16
    return (short)u;
}

// x [N_NODES*FEAT] fp32 -> bf16 (as short), 8 elems per thread
__global__ void cvt_x_kernel(const float* __restrict__ xin, short* __restrict__ xout, int n8) {
    int i = blockIdx.x * blockDim.x + threadIdx.x;
    if (i >= n8) return;
    const float* p = xin + (size_t)i * 8;
    short8 o;
#pragma unroll
    for (int j = 0; j < 8; ++j) o[j] = f2bf(p[j]);
    *(short8*)(xout + (size_t)i * 8) = o;
}

// W1 [256][128] fp32 -> W1t [128][256] bf16  (W1t[n][k] = W1[k][n])
__global__ void cvt_w1t_kernel(const float* __restrict__ w1, short* __restrict__ w1t) {
    int i = blockIdx.x * blockDim.x + threadIdx.x;   // i = n*256 + k
    int n = i >> 8, k = i & 255;
    w1t[i] = f2bf(w1[k * FEAT + n]);
}

// Main: per-edge MLP via MFMA. Block = 4 waves, each wave = 32 edges (two 16x16x32 M-tiles).
// W1t in LDS, chunk-major: chunk c (=k/8) 0..31, n 0..127, 8 bf16 each. 64 KB.
__global__ __launch_bounds__(256, 2) void edge_mlp_kernel(
    const short* __restrict__ xbf, const int* __restrict__ eidx,
    const short* __restrict__ w1t, const float* __restrict__ b1,
    const float* __restrict__ w2, const float* __restrict__ b2,
    float* __restrict__ out, int ngroups)
{
    __shared__ short lds_b[32 * 128 * 8];   // 65536 B

    const int tid = threadIdx.x;
    // stage W1t -> LDS, chunk-major [c][n]
    for (int j = tid; j < 32 * 128; j += 256) {
        int n = j & 127, c = j >> 7;
        short8 v = *(const short8*)(w1t + n * 256 + c * 8);
        *(short8*)(lds_b + ((c << 7) + n) * 8) = v;
    }
    __syncthreads();

    const int lane = tid & 63;
    const int wave = tid >> 6;
    const int nl = lane & 15;   // n-local (B) / m (A row) / col (C/D)
    const int q  = lane >> 4;   // quad

    // second-layer constants per lane: n = nt*16 + nl
    float b1v[8], w2v[8];
#pragma unroll
    for (int nt = 0; nt < 8; ++nt) { b1v[nt] = b1[nt * 16 + nl]; w2v[nt] = w2[nt * 16 + nl]; }
    const float bias2 = b2[0];

    for (int g = blockIdx.x; g < ngroups; g += gridDim.x) {
        const int ebase = g * 128 + wave * 32;   // this wave's 32 edges
        int e0 = ebase + nl, e1 = e0 + 16;
        bool v0 = e0 < N_EDGES, v1 = e1 < N_EDGES;
        int r0 = v0 ? eidx[e0] : 0;
        int c0 = v0 ? eidx[N_EDGES + e0] : 0;
        int r1 = v1 ? eidx[e1] : 0;
        int c1 = v1 ? eidx[N_EDGES + e1] : 0;

        // A-fragments: lane holds A[m=nl][k = 32s + 8q + j]; k<128 <=> s<4 (uniform)
        short8 a0[8], a1[8];
#pragma unroll
        for (int s = 0; s < 8; ++s) {
            int koff = s * 32 + q * 8;
            const short *p0, *p1;
            if (s < 4) {
                p0 = xbf + (size_t)r0 * FEAT + koff;
                p1 = xbf + (size_t)r1 * FEAT + koff;
            } else {
                p0 = xbf + (size_t)c0 * FEAT + (koff - 128);
                p1 = xbf + (size_t)c1 * FEAT + (koff - 128);
            }
            a0[s] = *(const short8*)p0;
            a1[s] = *(const short8*)p1;
        }

        floatx4 acc0[8], acc1[8];
#pragma unroll
        for (int nt = 0; nt < 8; ++nt) {
            acc0[nt] = (floatx4)(0.0f);
            acc1[nt] = (floatx4)(0.0f);
        }

#pragma unroll
        for (int s = 0; s < 8; ++s) {
            const int crow = (s * 4 + q) << 7;   // chunk row base (c * 128)
#pragma unroll
            for (int nt = 0; nt < 8; ++nt) {
                short8 bf = *(const short8*)(lds_b + ((crow + nt * 16 + nl) << 3));
                acc0[nt] = __builtin_amdgcn_mfma_f32_16x16x32_bf16(a0[s], bf, acc0[nt], 0, 0, 0);
                acc1[nt] = __builtin_amdgcn_mfma_f32_16x16x32_bf16(a1[s], bf, acc1[nt], 0, 0, 0);
            }
        }

        // epilogue: h = relu(acc + b1); o = sigmoid(h . W2 + b2)
        // C/D layout: lane holds D[m = q*4 + r][n = nt*16 + nl]
#pragma unroll
        for (int t = 0; t < 2; ++t) {
#pragma unroll
            for (int r = 0; r < 4; ++r) {
                float p = 0.0f;
#pragma unroll
                for (int nt = 0; nt < 8; ++nt) {
                    float h = (t == 0 ? acc0[nt][r] : acc1[nt][r]) + b1v[nt];
                    p = fmaf(fmaxf(h, 0.0f), w2v[nt], p);
                }
                p += __shfl_xor(p, 1);
                p += __shfl_xor(p, 2);
                p += __shfl_xor(p, 4);
                p += __shfl_xor(p, 8);
                if (nl == 0) {
                    int eo = ebase + t * 16 + q * 4 + r;
                    if (eo < N_EDGES) out[eo] = 1.0f / (1.0f + __expf(-(p + bias2)));
                }
            }
        }
    }
}

extern "C" void kernel_launch(void* const* d_in, const int* in_sizes, int n_in,
                              void* d_out, int out_size, void* d_ws, size_t ws_size,
                              hipStream_t stream) {
    const float* x  = (const float*)d_in[0];
    const int*   ei = (const int*)d_in[1];
    const float* W1 = (const float*)d_in[2];
    const float* b1 = (const float*)d_in[3];
    const float* W2 = (const float*)d_in[4];
    const float* b2 = (const float*)d_in[5];
    float* out = (float*)d_out;

    short* xbf = (short*)d_ws;                          // 12.8M shorts = 25.6 MB
    short* w1t = xbf + (size_t)N_NODES * FEAT;          // 32768 shorts

    int n8 = N_NODES * FEAT / 8;
    cvt_x_kernel<<<(n8 + 255) / 256, 256, 0, stream>>>(x, xbf, n8);
    cvt_w1t_kernel<<<32768 / 256, 256, 0, stream>>>(W1, w1t);

    int ngroups = (N_EDGES + 127) / 128;                // 4688
    edge_mlp_kernel<<<1024, 256, 0, stream>>>(xbf, ei, w1t, b1, W2, b2, out, ngroups);
}

// Round 2
// 168.036 us; speedup vs baseline: 1.6583x; 1.6583x over previous
//
#include <hip/hip_runtime.h>
#include <stdint.h>

#define N_NODES 100000
#define N_EDGES 600000
#define FEAT 128

typedef __attribute__((ext_vector_type(8))) short short8;
typedef __attribute__((ext_vector_type(4))) float floatx4;

__device__ __forceinline__ short f2bf(float f) {
    unsigned u = __builtin_bit_cast(unsigned, f);
    u = (u + 0x7FFFu + ((u >> 16) & 1u)) >> 16;   // RNE to bf16
    return (short)u;
}
__device__ __forceinline__ float bf2f(short s) {
    unsigned u = ((unsigned)(unsigned short)s) << 16;
    return __builtin_bit_cast(float, u);
}

// Build Wbt [n=256][k=128] bf16 where Wbt[n][k] = (n<128) ? W1[k][n] : W1[128+k][n-128]
// (i.e. columns of [W1_top | W1_bot], transposed for B-operand k-contiguity)
__global__ void cvt_w_kernel(const float* __restrict__ w1, short* __restrict__ wbt) {
    int i = blockIdx.x * 256 + threadIdx.x;   // 32768 = 256*128
    int n = i >> 7, k = i & 127;
    float f = (n < FEAT) ? w1[k * FEAT + n] : w1[(FEAT + k) * FEAT + (n - FEAT)];
    wbt[i] = f2bf(f);
}

// Y[100000][256] bf16 = X[100000][128] @ Wb[128][256]
// block = 4 waves, M-tile 64 (16 nodes/wave), full N=256. K=128 = 4 chunks of 32.
__global__ __launch_bounds__(256, 2) void node_gemm_kernel(
    const float* __restrict__ x, const short* __restrict__ wbt, short* __restrict__ y)
{
    __shared__ short lds_b[16 * 256 * 8];   // chunk-major [c=k/8][n], 64 KB

    const int tid = threadIdx.x;
    for (int j = tid; j < 16 * 256; j += 256) {
        int n = j & 255, c = j >> 8;
        short8 v = *(const short8*)(wbt + n * 128 + c * 8);
        *(short8*)(lds_b + ((c << 8) + n) * 8) = v;
    }
    __syncthreads();

    const int lane = tid & 63;
    const int wave = tid >> 6;
    const int nl = lane & 15;
    const int q  = lane >> 4;
    const int m0 = blockIdx.x * 64 + wave * 16;

    // A-fragment: lane holds A[m=nl][k=32s+8q+j], loaded fp32 and converted
    const int node = m0 + nl;
    const int nsrc = (node < N_NODES) ? node : 0;
    short8 a[4];
#pragma unroll
    for (int s = 0; s < 4; ++s) {
        const float* p = x + (size_t)nsrc * FEAT + s * 32 + q * 8;
        short8 av;
#pragma unroll
        for (int j = 0; j < 8; ++j) av[j] = f2bf(p[j]);
        a[s] = av;
    }

    floatx4 acc[16];
#pragma unroll
    for (int nt = 0; nt < 16; ++nt) acc[nt] = (floatx4)(0.0f);

#pragma unroll
    for (int s = 0; s < 4; ++s) {
        const int crow = (s * 4 + q) << 8;   // chunk c = s*4+q, row base c*256
#pragma unroll
        for (int nt = 0; nt < 16; ++nt) {
            short8 bf = *(const short8*)(lds_b + ((crow + nt * 16 + nl) << 3));
            acc[nt] = __builtin_amdgcn_mfma_f32_16x16x32_bf16(a[s], bf, acc[nt], 0, 0, 0);
        }
    }

    // C/D: lane holds D[m = q*4 + r][n = nt*16 + nl]
#pragma unroll
    for (int r = 0; r < 4; ++r) {
        int m = m0 + q * 4 + r;
        if (m >= N_NODES) continue;
        short* yr = y + (size_t)m * 256 + nl;
#pragma unroll
        for (int nt = 0; nt < 16; ++nt) yr[nt * 16] = f2bf(acc[nt][r]);
    }
}

// Per-edge: out = sigmoid(relu(Y[r].u + Y[c].v + b1) . W2 + b2). 16 lanes/edge, 8 feats/lane.
__global__ __launch_bounds__(256) void edge_kernel(
    const short* __restrict__ y, const int* __restrict__ eidx,
    const float* __restrict__ b1, const float* __restrict__ w2,
    const float* __restrict__ b2, float* __restrict__ out)
{
    int t = blockIdx.x * 256 + threadIdx.x;
    int e = t >> 4;
    int l = t & 15;
    if (e >= N_EDGES) return;

    int r = eidx[e];
    int c = eidx[N_EDGES + e];

    short8 uu = *(const short8*)(y + (size_t)r * 256 + l * 8);
    short8 vv = *(const short8*)(y + (size_t)c * 256 + 128 + l * 8);

    const float* b1p = b1 + l * 8;
    const float* w2p = w2 + l * 8;

    float p = 0.0f;
#pragma unroll
    for (int j = 0; j < 8; ++j) {
        float h = bf2f(uu[j]) + bf2f(vv[j]) + b1p[j];
        p = fmaf(fmaxf(h, 0.0f), w2p[j], p);
    }
    p += __shfl_xor(p, 1);
    p += __shfl_xor(p, 2);
    p += __shfl_xor(p, 4);
    p += __shfl_xor(p, 8);

    if (l == 0) out[e] = 1.0f / (1.0f + __expf(-(p + b2[0])));
}

extern "C" void kernel_launch(void* const* d_in, const int* in_sizes, int n_in,
                              void* d_out, int out_size, void* d_ws, size_t ws_size,
                              hipStream_t stream) {
    const float* x  = (const float*)d_in[0];
    const int*   ei = (const int*)d_in[1];
    const float* W1 = (const float*)d_in[2];
    const float* b1 = (const float*)d_in[3];
    const float* W2 = (const float*)d_in[4];
    const float* b2 = (const float*)d_in[5];
    float* out = (float*)d_out;

    short* ybf = (short*)d_ws;                          // 100000*256 shorts = 51.2 MB
    short* wbt = ybf + (size_t)N_NODES * 256;           // 32768 shorts

    cvt_w_kernel<<<32768 / 256, 256, 0, stream>>>(W1, wbt);

    int mblocks = (N_NODES + 63) / 64;                  // 1563
    node_gemm_kernel<<<mblocks, 256, 0, stream>>>(x, wbt, ybf);

    int eblocks = (N_EDGES * 16) / 256;                 // 37500
    edge_kernel<<<eblocks, 256, 0, stream>>>(ybf, ei, b1, W2, b2, out);
}